// Round 2
// baseline (1268.451 us; speedup 1.0000x reference)
//
#include <hip/hip_runtime.h>

// C = A @ dequant(B_packed, s); M=N=8192, K=4096, group=128, int4 zero-point 8.
// fp16 MFMA path: A cast fp32->fp16 (rtz), W dequantized to fp16 in-flight.
// 256x256x64 tile, 8 waves, double-buffered LDS, 2-phase pipeline, T1+T2 swizzles.

typedef _Float16 h2 __attribute__((ext_vector_type(2)));
typedef _Float16 h8 __attribute__((ext_vector_type(8)));
typedef float f32x4 __attribute__((ext_vector_type(4)));

#define MM 8192
#define NN 8192
#define KK 4096

__global__ __launch_bounds__(512, 2) void w4a32_gemm(
    const float* __restrict__ A, const int* __restrict__ Bq,
    const float* __restrict__ S, float* __restrict__ C)
{
  extern __shared__ __align__(16) char smem[];
  const int tid  = threadIdx.x;
  const int lane = tid & 63;
  const int wid  = tid >> 6;
  const int wm   = wid >> 2;   // 0..1
  const int wn   = wid & 3;    // 0..3
  const int ln15 = lane & 15;
  const int l16  = lane >> 4;

  // T1: XCD-aware bijective block swizzle (nwg=1024, 1024%8==0)
  const int bid = blockIdx.x;
  const int swz = (bid & 7) * 128 + (bid >> 3);
  const int bm  = swz >> 5;    // 0..31
  const int bn  = swz & 31;    // 0..31

  // ---- A staging: thread -> (row am, 32-k half akh) ----
  const int am  = tid >> 1;
  const int akh = tid & 1;
  const float* Ap = A + (size_t)(bm * 256 + am) * KK + akh * 32;

  // ---- B staging: thread -> (packed row bkp == k-octet, 4 cols at bn4) ----
  const int bkp = tid & 7;
  const int bn4 = (tid >> 3) << 2;
  const int*   Bp = Bq + (size_t)bkp * NN + bn * 256 + bn4;
  const float* Sp = S + bn * 256 + bn4;

  int awoff[4], bwoff[4];
#pragma unroll
  for (int j = 0; j < 4; ++j)
    awoff[j] = (am * 128 + (akh * 4 + j) * 16) ^ ((am & 7) << 4);
#pragma unroll
  for (int i = 0; i < 4; ++i)
    bwoff[i] = ((bn4 + i) * 128 + bkp * 16) ^ (((bn4 + i) & 7) << 4);

  f32x4 acc[8][4];
#pragma unroll
  for (int mi = 0; mi < 8; ++mi)
#pragma unroll
    for (int ni = 0; ni < 4; ++ni)
      acc[mi][ni] = (f32x4){0.f, 0.f, 0.f, 0.f};

  float4 av[8]; int4 wq; float4 sv;

  auto load_stage = [&](int koff) {
    const float4* ap = (const float4*)(Ap + koff);
#pragma unroll
    for (int j = 0; j < 8; ++j) av[j] = ap[j];
    wq = *(const int4*)(Bp + (size_t)(koff >> 6) * (8 * NN));
    sv = *(const float4*)(Sp + (size_t)(koff >> 7) * NN);
  };

  auto write_stage = [&](char* sa, char* sb) {
    // A: fp32 -> fp16 pairs with k-perm [0,4,1,5,2,6,3,7] per octet
#pragma unroll
    for (int j = 0; j < 4; ++j) {
      float4 f0 = av[2 * j], f1 = av[2 * j + 1];
      auto p0 = __builtin_amdgcn_cvt_pkrtz(f0.x, f1.x);
      auto p1 = __builtin_amdgcn_cvt_pkrtz(f0.y, f1.y);
      auto p2 = __builtin_amdgcn_cvt_pkrtz(f0.z, f1.z);
      auto p3 = __builtin_amdgcn_cvt_pkrtz(f0.w, f1.w);
      int4 wd;
      wd.x = __builtin_bit_cast(int, p0);
      wd.y = __builtin_bit_cast(int, p1);
      wd.z = __builtin_bit_cast(int, p2);
      wd.w = __builtin_bit_cast(int, p3);
      *(int4*)(sa + awoff[j]) = wd;
    }
    // B: nibble pairs (qj, qj+4) -> fp16(1024+q) via and_or magic, then
    // (x - 1032) * s  == (q-8)*s  (exact subtract, one rounding on mul)
    const h2 cM = {(_Float16)(-1032.f), (_Float16)(-1032.f)};
#pragma unroll
    for (int i = 0; i < 4; ++i) {
      unsigned w = (unsigned)((i == 0) ? wq.x : (i == 1) ? wq.y : (i == 2) ? wq.z : wq.w);
      float   sc = (i == 0) ? sv.x : (i == 1) ? sv.y : (i == 2) ? sv.z : sv.w;
      _Float16 sh = (_Float16)sc;
      h2 s2 = {sh, sh};
      unsigned x0 = ( w        & 0x000F000Fu) | 0x64006400u;
      unsigned x1 = ((w >> 4)  & 0x000F000Fu) | 0x64006400u;
      unsigned x2 = ((w >> 8)  & 0x000F000Fu) | 0x64006400u;
      unsigned x3 = ((w >> 12) & 0x000F000Fu) | 0x64006400u;
      h2 r0 = (__builtin_bit_cast(h2, x0) + cM) * s2;
      h2 r1 = (__builtin_bit_cast(h2, x1) + cM) * s2;
      h2 r2 = (__builtin_bit_cast(h2, x2) + cM) * s2;
      h2 r3 = (__builtin_bit_cast(h2, x3) + cM) * s2;
      int4 wd;
      wd.x = __builtin_bit_cast(int, r0);
      wd.y = __builtin_bit_cast(int, r1);
      wd.z = __builtin_bit_cast(int, r2);
      wd.w = __builtin_bit_cast(int, r3);
      *(int4*)(sb + bwoff[i]) = wd;
    }
  };

  auto compute = [&](const char* sa, const char* sb) {
#pragma unroll
    for (int ks = 0; ks < 2; ++ks) {
      h8 bf[4];
#pragma unroll
      for (int ni = 0; ni < 4; ++ni) {
        int row = wn * 64 + ni * 16 + ln15;
        int off = (row * 128 + (ks * 4 + l16) * 16) ^ ((row & 7) << 4);
        bf[ni] = *(const h8*)(sb + off);
      }
#pragma unroll
      for (int mi = 0; mi < 8; ++mi) {
        int row = wm * 128 + mi * 16 + ln15;
        int off = (row * 128 + (ks * 4 + l16) * 16) ^ ((row & 7) << 4);
        h8 af = *(const h8*)(sa + off);
#pragma unroll
        for (int ni = 0; ni < 4; ++ni)
          acc[mi][ni] = __builtin_amdgcn_mfma_f32_16x16x32_f16(af, bf[ni], acc[mi][ni], 0, 0, 0);
      }
    }
  };

  // prologue
  load_stage(0);
  write_stage(smem, smem + 32768);
  __syncthreads();

  int cur = 0;
  for (int t = 0; t < 63; ++t) {
    load_stage((t + 1) * 64);                 // issue next-tile loads (hide under MFMA)
    compute(smem + cur * 65536, smem + cur * 65536 + 32768);
    int nxt = cur ^ 1;
    write_stage(smem + nxt * 65536, smem + nxt * 65536 + 32768);  // vmcnt wait inserted here
    __syncthreads();
    cur = nxt;
  }
  compute(smem + cur * 65536, smem + cur * 65536 + 32768);

  // epilogue: C/D layout col=lane&15, row=(lane>>4)*4+j
  float* Cp = C + (size_t)(bm * 256 + wm * 128) * NN + bn * 256 + wn * 64;
#pragma unroll
  for (int mi = 0; mi < 8; ++mi)
#pragma unroll
    for (int ni = 0; ni < 4; ++ni)
#pragma unroll
      for (int j = 0; j < 4; ++j)
        Cp[(size_t)(mi * 16 + l16 * 4 + j) * NN + ni * 16 + ln15] = acc[mi][ni][j];
}

extern "C" void kernel_launch(void* const* d_in, const int* in_sizes, int n_in,
                              void* d_out, int out_size, void* d_ws, size_t ws_size,
                              hipStream_t stream) {
  const float* A  = (const float*)d_in[0];
  const int*   Bq = (const int*)d_in[1];
  const float* S  = (const float*)d_in[2];
  float* C = (float*)d_out;

  (void)hipFuncSetAttribute((const void*)w4a32_gemm,
                            hipFuncAttributeMaxDynamicSharedMemorySize, 131072);

  dim3 grid(1024), block(512);
  w4a32_gemm<<<grid, block, 131072, stream>>>(A, Bq, S, C);
}